// Round 6
// baseline (586.239 us; speedup 1.0000x reference)
//
#include <hip/hip_runtime.h>
#include <stdint.h>
#include <stddef.h>

typedef __bf16 bf16;
typedef __bf16 bf16x8 __attribute__((ext_vector_type(8)));
typedef float  f32x4  __attribute__((ext_vector_type(4)));

#define GLOBAL_AS(p) ((const __attribute__((address_space(1))) void*)(p))
#define LDS_AS(p)    ((__attribute__((address_space(3))) void*)(p))

__device__ __forceinline__ void gload_lds16(const bf16* g, bf16* l) {
    // global_load_lds_dwordx4: LDS dest = wave-uniform base + lane*16 (caller guarantees)
    __builtin_amdgcn_global_load_lds(GLOBAL_AS(g), LDS_AS(l), 16, 0, 0);
}

// ---------------------------------------------------------------------------
// x (f32) -> bf16, 8 elems/thread
// ---------------------------------------------------------------------------
__global__ __launch_bounds__(256)
void convert_x_kernel(const float* __restrict__ x, bf16* __restrict__ xb, long n8) {
    long t = (long)blockIdx.x * blockDim.x + threadIdx.x;
    if (t >= n8) return;
    const f32x4* p = (const f32x4*)(x + t * 8);
    f32x4 a = p[0], b = p[1];
    bf16x8 v;
#pragma unroll
    for (int j = 0; j < 4; ++j) { v[j] = (bf16)a[j]; v[4 + j] = (bf16)b[j]; }
    *(bf16x8*)(xb + t * 8) = v;
}

// ---------------------------------------------------------------------------
// qweight [K/8, N] int32 (8 nibbles along K) + f32 scales/qzeros [K/G, N]
//   -> Wt [N, K] bf16 ; Wt[o][k] = s[g][o]*(nib - z[g][o]), g = k/G
// Thread t: o = t/(K/8), r = t%(K/8) -> one coalesced 16B store.
// ---------------------------------------------------------------------------
__global__ __launch_bounds__(256)
void dequant_wt_kernel(const uint32_t* __restrict__ qw,
                       const float* __restrict__ scales,
                       const float* __restrict__ qzeros,
                       bf16* __restrict__ Wt,
                       int N, int K, int rows_per_group) {
    int rows = K >> 3;
    int t = blockIdx.x * blockDim.x + threadIdx.x;
    int o = t / rows;
    int r = t - o * rows;
    if (o >= N) return;
    uint32_t q = qw[(size_t)r * N + o];
    int g = r / rows_per_group;
    float s = scales[(size_t)g * N + o];
    float z = qzeros[(size_t)g * N + o];
    float nsz = -s * z;
    bf16x8 v;
#pragma unroll
    for (int j = 0; j < 8; ++j)
        v[j] = (bf16)fmaf((float)((q >> (4 * j)) & 15u), s, nsz);
    *(bf16x8*)(Wt + (size_t)o * K + (size_t)r * 8) = v;
}

// ---------------------------------------------------------------------------
// GEMM: out[m,n] = sum_k x[m,k]*Wt[n,k] + bias[n]   (f32 out, f32 bias)
// 128x128 tile, BK=32, 4 waves (2x2), 4x4 of mfma_f32_16x16x32_bf16.
// PREP (!FUSED): bf16 A (xb) + bf16 Bt from ws, global_load_lds staging (m97).
// FUSED: f32 x converted in-flight + B dequantized from qweight into LDS.
// ---------------------------------------------------------------------------
constexpr int BM = 128, BN = 128, BK = 32;

template <bool FUSED>
__global__ __launch_bounds__(256)
void gemm_kernel(const bf16* __restrict__ Ab,       // [M,K] bf16 (PREP)
                 const float* __restrict__ Af,      // [M,K] f32 (FUSED)
                 const bf16* __restrict__ Bt,       // [N,K] bf16 (PREP)
                 const uint32_t* __restrict__ qw,   // [K/8,N] (FUSED)
                 const float* __restrict__ scales,  // [K/G,N] f32
                 const float* __restrict__ qzeros,  // [K/G,N] f32
                 const float* __restrict__ bias,    // [N] f32
                 float* __restrict__ out,           // [M,N] f32
                 int M, int N, int K, int G) {
    __shared__ __align__(16) bf16 As[BM * BK];
    __shared__ __align__(16) bf16 Bs[BN * BK];

    const int tid  = threadIdx.x;
    const int lane = tid & 63;
    const int wave = tid >> 6;
    const int wm = wave & 1;
    const int wn = wave >> 1;
    const int m0 = blockIdx.y * BM;
    const int n0 = blockIdx.x * BN;

    const int lrow = lane & 15;
    const int lk8  = (lane >> 4) * 8;

    f32x4 acc[4][4];
#pragma unroll
    for (int i = 0; i < 4; ++i)
#pragma unroll
        for (int j = 0; j < 4; ++j) acc[i][j] = (f32x4){0.f, 0.f, 0.f, 0.f};

    for (int kt = 0; kt < K; kt += BK) {
        if (!FUSED) {
            // m97 staging: 512 chunks of 16B per tile, 2 per thread
#pragma unroll
            for (int it = 0; it < 2; ++it) {
                const int c = tid + it * 256;
                const int row = c >> 2;
                const int kc  = (c & 3) * 8;
                gload_lds16(Ab + (size_t)(m0 + row) * K + kt + kc, As + c * 8);
                gload_lds16(Bt + (size_t)(n0 + row) * K + kt + kc, Bs + c * 8);
            }
        } else {
            // A: f32 load + convert
#pragma unroll
            for (int it = 0; it < 2; ++it) {
                const int c = tid + it * 256;
                const int row = c >> 2;
                const int kc  = (c & 3) * 8;
                const f32x4* p = (const f32x4*)(Af + (size_t)(m0 + row) * K + kt + kc);
                f32x4 a = p[0], b = p[1];
                bf16x8 v;
#pragma unroll
                for (int j = 0; j < 4; ++j) { v[j] = (bf16)a[j]; v[4 + j] = (bf16)b[j]; }
                *(bf16x8*)(As + row * BK + kc) = v;
            }
            // B: dequant from qweight (G=64 >= 32: one group per k-tile)
            const int g = kt / G;
#pragma unroll
            for (int it = 0; it < 2; ++it) {
                const int idx = tid + it * 256;
                const int rl = idx >> 7;          // 0..3
                const int nl = idx & 127;
                uint32_t q = qw[(size_t)(kt / 8 + rl) * N + n0 + nl];
                float s = scales[(size_t)g * N + n0 + nl];
                float z = qzeros[(size_t)g * N + n0 + nl];
                float nsz = -s * z;
                bf16x8 v;
#pragma unroll
                for (int j = 0; j < 8; ++j)
                    v[j] = (bf16)fmaf((float)((q >> (4 * j)) & 15u), s, nsz);
                *(bf16x8*)(Bs + nl * BK + rl * 8) = v;
            }
        }
        __syncthreads();

        bf16x8 a[4], b[4];
#pragma unroll
        for (int i = 0; i < 4; ++i)
            a[i] = *(const bf16x8*)(As + (wm * 64 + i * 16 + lrow) * BK + lk8);
#pragma unroll
        for (int j = 0; j < 4; ++j)
            b[j] = *(const bf16x8*)(Bs + (wn * 64 + j * 16 + lrow) * BK + lk8);

#pragma unroll
        for (int i = 0; i < 4; ++i)
#pragma unroll
            for (int j = 0; j < 4; ++j)
                acc[i][j] = __builtin_amdgcn_mfma_f32_16x16x32_bf16(
                    a[i], b[j], acc[i][j], 0, 0, 0);
        __syncthreads();
    }

    // epilogue: D layout col=lane&15 (n), row=(lane>>4)*4+reg (m); f32 out
#pragma unroll
    for (int j = 0; j < 4; ++j) {
        const int col = n0 + wn * 64 + j * 16 + (lane & 15);
        const float bv = bias[col];
#pragma unroll
        for (int i = 0; i < 4; ++i) {
            const int rbase = m0 + wm * 64 + i * 16 + (lane >> 4) * 4;
#pragma unroll
            for (int r = 0; r < 4; ++r)
                out[(size_t)(rbase + r) * N + col] = acc[i][j][r] + bv;
        }
    }
}

extern "C" void kernel_launch(void* const* d_in, const int* in_sizes, int n_in,
                              void* d_out, int out_size, void* d_ws, size_t ws_size,
                              hipStream_t stream) {
    // fp16 reference tensors are stored as FLOAT32 by the harness ("else float*")
    const float*    x      = (const float*)d_in[0];
    const uint32_t* qw     = (const uint32_t*)d_in[1];
    const float*    scales = (const float*)d_in[2];
    const float*    qzeros = (const float*)d_in[3];
    const float*    bias   = (const float*)d_in[4];
    float*          out    = (float*)d_out;

    const int N = in_sizes[4];                 // 4096
    const int K = (in_sizes[1] / N) * 8;       // 4096
    const int M = in_sizes[0] / K;             // 8192
    const int G = K / (in_sizes[2] / N);       // 64

    dim3 grid(N / BN, M / BM);
    const size_t xb_bytes = (size_t)M * K * sizeof(bf16);   // 64 MB
    const size_t wt_bytes = (size_t)N * K * sizeof(bf16);   // 32 MB

    if (ws_size >= xb_bytes + wt_bytes) {
        bf16* Xb = (bf16*)d_ws;
        bf16* Wt = (bf16*)((char*)d_ws + xb_bytes);
        const long n8 = (long)M * K / 8;
        convert_x_kernel<<<(int)((n8 + 255) / 256), 256, 0, stream>>>(x, Xb, n8);
        const int total = (K >> 3) * N;
        dequant_wt_kernel<<<(total + 255) / 256, 256, 0, stream>>>(
            qw, scales, qzeros, Wt, N, K, G / 8);
        gemm_kernel<false><<<grid, 256, 0, stream>>>(
            Xb, nullptr, Wt, nullptr, scales, qzeros, bias, out, M, N, K, G);
    } else {
        gemm_kernel<true><<<grid, 256, 0, stream>>>(
            nullptr, x, nullptr, qw, scales, qzeros, bias, out, M, N, K, G);
    }
}

// Round 7
// 561.746 us; speedup vs baseline: 1.0436x; 1.0436x over previous
//
#include <hip/hip_runtime.h>
#include <stdint.h>
#include <stddef.h>

typedef __bf16 bf16;
typedef __bf16 bf16x8 __attribute__((ext_vector_type(8)));
typedef float  f32x4  __attribute__((ext_vector_type(4)));

#define GLOBAL_AS(p) ((const __attribute__((address_space(1))) void*)(p))
#define LDS_AS(p)    ((__attribute__((address_space(3))) void*)(p))

__device__ __forceinline__ void gload_lds16(const bf16* g, bf16* l) {
    // global_load_lds_dwordx4: LDS dest = wave-uniform base + lane*16 (caller guarantees)
    __builtin_amdgcn_global_load_lds(GLOBAL_AS(g), LDS_AS(l), 16, 0, 0);
}

// ---------------------------------------------------------------------------
// x (f32) -> bf16, 8 elems/thread, both directions coalesced
// ---------------------------------------------------------------------------
__global__ __launch_bounds__(256)
void convert_x_kernel(const float* __restrict__ x, bf16* __restrict__ xb, long n8) {
    long t = (long)blockIdx.x * blockDim.x + threadIdx.x;
    if (t >= n8) return;
    const f32x4* p = (const f32x4*)(x + t * 8);
    f32x4 a = p[0], b = p[1];
    bf16x8 v;
#pragma unroll
    for (int j = 0; j < 4; ++j) { v[j] = (bf16)a[j]; v[4 + j] = (bf16)b[j]; }
    *(bf16x8*)(xb + t * 8) = v;
}

// ---------------------------------------------------------------------------
// Dequant to K-TILED layout: Wt[K/32][N][32], Wt[kt][o][cc] = W^T[o][kt*32+cc]
//   = s[g][o]*(nib - z[g][o]),  nib = (qw[k/8, o] >> 4*(k%8)) & 15, g = k/G.
// Wave mapping: lane l -> c = l&3 (qw row within quad), oo = l>>2 (o offset).
//   loads  qw[(4rq+c)*N + o]   : 4 x 64B coalesced segments per wave
//   stores base + l*16B        : 1KB contiguous per wave
// ---------------------------------------------------------------------------
__global__ __launch_bounds__(256)
void dequant_wt_tiled_kernel(const uint32_t* __restrict__ qw,
                             const float* __restrict__ scales,
                             const float* __restrict__ qzeros,
                             bf16* __restrict__ Wt,
                             int N, int K, int rows_per_group) {
    const int i = blockIdx.x * 256 + threadIdx.x;
    const int w = i >> 6, l = i & 63;
    const int nrq = K >> 5;                  // quad-rows (32 k each)
    const int rq = w % nrq;
    const int o  = (w / nrq) * 16 + (l >> 2);
    const int c  = l & 3;
    const int r  = rq * 4 + c;               // qweight row; k = r*8 + j
    if (o >= N) return;
    const uint32_t q = qw[(size_t)r * N + o];
    const int g = r / rows_per_group;
    const float s = scales[(size_t)g * N + o];
    const float z = qzeros[(size_t)g * N + o];
    const float nsz = -s * z;
    bf16x8 v;
#pragma unroll
    for (int j = 0; j < 8; ++j)
        v[j] = (bf16)fmaf((float)((q >> (4 * j)) & 15u), s, nsz);
    *(bf16x8*)(Wt + (size_t)rq * N * 32 + (size_t)o * 32 + c * 8) = v;
}

// ---------------------------------------------------------------------------
// GEMM: out[m,n] = sum_k x[m,k]*W^T[n,k] + bias[n]   (f32 out/bias)
// 128x128 tile, BK=32, 4 waves (2x2), 4x4 of mfma_f32_16x16x32_bf16.
// PREP: A = Xb[M][K] bf16, B = Wt tiled [K/32][N][32] -> one contiguous 32KB
//       global_load_lds block per (kt,n0) tile. LDS image identical to R6.
// FUSED fallback: f32 x + qweight dequant in-flight (small-ws only).
// ---------------------------------------------------------------------------
constexpr int BM = 128, BN = 128, BK = 32;

template <bool FUSED>
__global__ __launch_bounds__(256)
void gemm_kernel(const bf16* __restrict__ Ab,       // [M,K] bf16 (PREP)
                 const float* __restrict__ Af,      // [M,K] f32 (FUSED)
                 const bf16* __restrict__ Bt,       // tiled [K/32][N][32] (PREP)
                 const uint32_t* __restrict__ qw,   // [K/8,N] (FUSED)
                 const float* __restrict__ scales,  // [K/G,N] f32
                 const float* __restrict__ qzeros,  // [K/G,N] f32
                 const float* __restrict__ bias,    // [N] f32
                 float* __restrict__ out,           // [M,N] f32
                 int M, int N, int K, int G) {
    __shared__ __align__(16) bf16 As[BM * BK];
    __shared__ __align__(16) bf16 Bs[BN * BK];

    const int tid  = threadIdx.x;
    const int lane = tid & 63;
    const int wave = tid >> 6;
    const int wm = wave & 1;
    const int wn = wave >> 1;
    const int m0 = blockIdx.y * BM;
    const int n0 = blockIdx.x * BN;

    const int lrow = lane & 15;
    const int lk8  = (lane >> 4) * 8;

    f32x4 acc[4][4];
#pragma unroll
    for (int i = 0; i < 4; ++i)
#pragma unroll
        for (int j = 0; j < 4; ++j) acc[i][j] = (f32x4){0.f, 0.f, 0.f, 0.f};

    for (int kt = 0; kt < K; kt += BK) {
        if (!FUSED) {
            const bf16* bsrc = Bt + (size_t)(kt >> 5) * N * 32 + (size_t)n0 * 32;
#pragma unroll
            for (int it = 0; it < 2; ++it) {
                const int c = tid + it * 256;         // 512 chunks of 16B
                const int row = c >> 2;
                const int kc  = (c & 3) * 8;
                gload_lds16(Ab + (size_t)(m0 + row) * K + kt + kc, As + c * 8);
                gload_lds16(bsrc + c * 8, Bs + c * 8);
            }
        } else {
#pragma unroll
            for (int it = 0; it < 2; ++it) {
                const int c = tid + it * 256;
                const int row = c >> 2;
                const int kc  = (c & 3) * 8;
                const f32x4* p = (const f32x4*)(Af + (size_t)(m0 + row) * K + kt + kc);
                f32x4 a = p[0], b = p[1];
                bf16x8 v;
#pragma unroll
                for (int j = 0; j < 4; ++j) { v[j] = (bf16)a[j]; v[4 + j] = (bf16)b[j]; }
                *(bf16x8*)(As + row * BK + kc) = v;
            }
            const int g = kt / G;
#pragma unroll
            for (int it = 0; it < 2; ++it) {
                const int idx = tid + it * 256;
                const int rl = idx >> 7;
                const int nl = idx & 127;
                uint32_t q = qw[(size_t)(kt / 8 + rl) * N + n0 + nl];
                float s = scales[(size_t)g * N + n0 + nl];
                float z = qzeros[(size_t)g * N + n0 + nl];
                float nsz = -s * z;
                bf16x8 v;
#pragma unroll
                for (int j = 0; j < 8; ++j)
                    v[j] = (bf16)fmaf((float)((q >> (4 * j)) & 15u), s, nsz);
                *(bf16x8*)(Bs + nl * BK + rl * 8) = v;
            }
        }
        __syncthreads();

        bf16x8 a[4], b[4];
#pragma unroll
        for (int i = 0; i < 4; ++i)
            a[i] = *(const bf16x8*)(As + (wm * 64 + i * 16 + lrow) * BK + lk8);
#pragma unroll
        for (int j = 0; j < 4; ++j)
            b[j] = *(const bf16x8*)(Bs + (wn * 64 + j * 16 + lrow) * BK + lk8);

#pragma unroll
        for (int i = 0; i < 4; ++i)
#pragma unroll
            for (int j = 0; j < 4; ++j)
                acc[i][j] = __builtin_amdgcn_mfma_f32_16x16x32_bf16(
                    a[i], b[j], acc[i][j], 0, 0, 0);
        __syncthreads();
    }

    // epilogue: D layout col=lane&15 (n), row=(lane>>4)*4+reg (m); f32 out
#pragma unroll
    for (int j = 0; j < 4; ++j) {
        const int col = n0 + wn * 64 + j * 16 + (lane & 15);
        const float bv = bias[col];
#pragma unroll
        for (int i = 0; i < 4; ++i) {
            const int rbase = m0 + wm * 64 + i * 16 + (lane >> 4) * 4;
#pragma unroll
            for (int r = 0; r < 4; ++r)
                out[(size_t)(rbase + r) * N + col] = acc[i][j][r] + bv;
        }
    }
}

extern "C" void kernel_launch(void* const* d_in, const int* in_sizes, int n_in,
                              void* d_out, int out_size, void* d_ws, size_t ws_size,
                              hipStream_t stream) {
    // fp16 reference tensors are stored as FLOAT32 by the harness
    const float*    x      = (const float*)d_in[0];
    const uint32_t* qw     = (const uint32_t*)d_in[1];
    const float*    scales = (const float*)d_in[2];
    const float*    qzeros = (const float*)d_in[3];
    const float*    bias   = (const float*)d_in[4];
    float*          out    = (float*)d_out;

    const int N = in_sizes[4];                 // 4096
    const int K = (in_sizes[1] / N) * 8;       // 4096
    const int M = in_sizes[0] / K;             // 8192
    const int G = K / (in_sizes[2] / N);       // 64

    dim3 grid(N / BN, M / BM);
    const size_t xb_bytes = (size_t)M * K * sizeof(bf16);   // 64 MB
    const size_t wt_bytes = (size_t)N * K * sizeof(bf16);   // 32 MB

    if (ws_size >= xb_bytes + wt_bytes) {
        bf16* Xb = (bf16*)d_ws;
        bf16* Wt = (bf16*)((char*)d_ws + xb_bytes);
        const long n8 = (long)M * K / 8;
        convert_x_kernel<<<(int)((n8 + 255) / 256), 256, 0, stream>>>(x, Xb, n8);
        // waves = (N/16) * (K/32); threads = waves*64
        const long dq_threads = ((long)N / 16) * (K >> 5) * 64;
        dequant_wt_tiled_kernel<<<(int)((dq_threads + 255) / 256), 256, 0, stream>>>(
            qw, scales, qzeros, Wt, N, K, G / 8);
        gemm_kernel<false><<<grid, 256, 0, stream>>>(
            Xb, nullptr, Wt, nullptr, scales, qzeros, bias, out, M, N, K, G);
    } else {
        gemm_kernel<true><<<grid, 256, 0, stream>>>(
            nullptr, x, nullptr, qw, scales, qzeros, bias, out, M, N, K, G);
    }
}